// Round 6
// baseline (51.676 us; speedup 1.0000x reference)
//
#include <hip/hip_runtime.h>

// ---------- types ----------
typedef __attribute__((ext_vector_type(8))) short bf16x8;
typedef __attribute__((ext_vector_type(4))) float f32x4;

__device__ __forceinline__ short f2bf(float f) {
  unsigned u = __builtin_bit_cast(unsigned, f);
  u += 0x7fffu + ((u >> 16) & 1u);   // round-to-nearest-even
  return (short)(u >> 16);
}

// ---------- layout ----------
// IN=4096, OUT=4096, RANK=1024, GROUP=128, PACK=8
// GEMM: out[n*4096+m] = sum_r W_V(m,r)*S(r) * W_U(r,n)
// A,B stored FRAGMENT-MAJOR (see R5): each 1024-B block is one MFMA fragment
// in lane order -> GLL copies contiguously, ds_read_b128 stride-1 (no conflicts).
//   element addr = ((panel*16 + kt)*32 + blk)*512 + lane*8 + e
//   A blk = h*16 + i*2 + kk ; B blk = q*8 + j*2 + kk

// ---------- stage 1: fused dequant (V -> A, U -> B) ----------
__global__ __launch_bounds__(256) void dequant_fused(
    const int* __restrict__ qw_V, const int* __restrict__ qz_V,
    const float* __restrict__ sc_V, const float* __restrict__ S,
    short* __restrict__ A,
    const int* __restrict__ qw_U, const int* __restrict__ qz_U,
    const float* __restrict__ sc_U, short* __restrict__ B) {
  const int bid = blockIdx.x;
  if (bid < 2048) {
    const int t    = bid * 256 + threadIdx.x;        // 0..524287
    const int tile = t >> 11;
    const int blk  = (t >> 6) & 31;
    const int lane = t & 63;
    const int panel = tile >> 4, kt = tile & 15;
    const int m  = (panel << 8) + (((blk >> 4) & 1) << 7) + (((blk >> 1) & 7) << 4) + (lane & 15);
    const int r0 = (kt << 6) + ((blk & 1) << 5) + ((lane >> 4) << 3);
    const int g  = m >> 7;
    const int sh = (m & 7) << 2;
    const int zw = qz_V[(g << 7) + (r0 >> 3)];
    const int*   wq  = qw_V + (m >> 3) * 1024 + r0;
    const float* scp = sc_V + (g << 10) + r0;
    const float* sp  = S + r0;
    bf16x8 res;
#pragma unroll
    for (int e = 0; e < 8; ++e) {
      int q = (wq[e] >> sh) & 15;
      int z = ((zw >> (e << 2)) & 15) + 1;
      res[e] = f2bf((float)(q - z) * scp[e] * sp[e]);
    }
    *(bf16x8*)(A + ((size_t)t << 3)) = res;
  } else {
    const int t    = (bid - 2048) * 256 + threadIdx.x;
    const int tile = t >> 11;
    const int blk  = (t >> 6) & 31;
    const int lane = t & 63;
    const int panel = tile >> 4, kt = tile & 15;
    const int n  = (panel << 8) + (((blk >> 3) & 3) << 6) + (((blk >> 1) & 3) << 4) + (lane & 15);
    const int r0 = (kt << 6) + ((blk & 1) << 5) + ((lane >> 4) << 3);
    const int w  = qw_U[(r0 >> 3) * 4096 + n];
    const int g  = r0 >> 7;
    const int zw = qz_U[(g << 9) + (n >> 3)];
    const int z  = ((zw >> ((n & 7) << 2)) & 15) + 1;
    const float s = sc_U[(g << 12) + n];
    bf16x8 res;
#pragma unroll
    for (int e = 0; e < 8; ++e) {
      int q = (w >> (e << 2)) & 15;
      res[e] = f2bf((float)(q - z) * s);
    }
    *(bf16x8*)(B + ((size_t)t << 3)) = res;
  }
}

// ---------- stage 2: 256x256, BK=64, 8-wave, pipelined 4-quadrant K-tile ----
// LDS: buf b at b*65536; A blocks at +0, B blocks at +32768.
// Per K-tile: front-load 16 ds_reads, counted lgkmcnt(4)/(8)/(0) between the
// 4 MFMA quadrant clusters; 3 barriers/kt (post-ph1 = B safe, post-ph2 = A
// safe, end = buffer publish). Staging: ph2 -> B(kt+2), ph3 -> A(kt+2).
// vmcnt: 8 outstanding entering iter; +4 (STGB) +4 (STGA); vmcnt(8) retires
// exactly tile kt+1's 8 GLLs. kt==14 -> vmcnt(0).
#define GLL(g, l)                                                              \
  __builtin_amdgcn_global_load_lds(                                            \
      (const __attribute__((address_space(1))) void*)(g),                      \
      (__attribute__((address_space(3))) void*)(l), 16, 0, 0)

__global__ __launch_bounds__(512, 2) void gemm256(const short* __restrict__ A,
                                                  const short* __restrict__ B,
                                                  float* __restrict__ out) {
  __shared__ __align__(16) char lds[131072];
  const int tid  = threadIdx.x;          // 0..511
  const int lane = tid & 63;
  const int wid  = tid >> 6;             // 0..7
  const int wm   = wid >> 2;             // 0..1
  const int wn   = wid & 3;              // 0..3
  // T1: bijective XCD swizzle (256 = 8 XCDs x 32)
  const int bid = ((blockIdx.x & 7) << 5) | (blockIdx.x >> 3);
  const int mp = bid >> 4;
  const int np = bid & 15;

  // staging: wave wid copies A blocks wid*4..+3 and B blocks wid*4..+3
  const short* gA = A + ((size_t)(mp * 16) << 14) + (wid << 11) + (lane << 3);
  const short* gB = B + ((size_t)(np * 16) << 14) + (wid << 11) + (lane << 3);

#define STGA(buf, ktv) do {                                                    \
    const short* s_ = gA + ((ktv) << 14);                                      \
    char* d_ = lds + (buf) + (wid << 12);                                      \
    GLL(s_,        d_);                                                        \
    GLL(s_ +  512, d_ + 1024);                                                 \
    GLL(s_ + 1024, d_ + 2048);                                                 \
    GLL(s_ + 1536, d_ + 3072);                                                 \
  } while (0)
#define STGB(buf, ktv) do {                                                    \
    const short* s_ = gB + ((ktv) << 14);                                      \
    char* d_ = lds + (buf) + 32768 + (wid << 12);                              \
    GLL(s_,        d_);                                                        \
    GLL(s_ +  512, d_ + 1024);                                                 \
    GLL(s_ + 1024, d_ + 2048);                                                 \
    GLL(s_ + 1536, d_ + 3072);                                                 \
  } while (0)

  // fragment read bases: A block (h,i,kk) at h*16384 + (i*2+kk)*1024 + lane*16
  const char* Ard = lds + (wm << 14) + (lane << 4);
  const char* Brd = lds + 32768 + (wn << 13) + (lane << 4);

  f32x4 acc[8][4];
#pragma unroll
  for (int mi = 0; mi < 8; ++mi)
#pragma unroll
    for (int ni = 0; ni < 4; ++ni) acc[mi][ni] = f32x4{0.f, 0.f, 0.f, 0.f};

  bf16x8 alo[4][2], ahi[4][2], bh0[2][2], bh1[2][2];

  // ---- prologue: tiles 0,1 staged in steady-state FIFO order (B then A) ----
  STGB(0, 0);
  STGA(0, 0);
  STGB(65536, 1);
  STGA(65536, 1);
  asm volatile("s_waitcnt vmcnt(8)" ::: "memory");   // tile 0 fully landed
  __builtin_amdgcn_s_barrier();

  for (int kt = 0; kt < 16; ++kt) {
    const int curbuf = (kt & 1) << 16;   // buffer of tile kt (and kt+2)

    // ---- front-load 16 ds_reads: alo(8), bh0(4), bh1(4) ----
#pragma unroll
    for (int i = 0; i < 4; ++i) {
      alo[i][0] = *(const bf16x8*)(Ard + curbuf + (i << 11));
      alo[i][1] = *(const bf16x8*)(Ard + curbuf + (i << 11) + 1024);
    }
#pragma unroll
    for (int j = 0; j < 2; ++j) {
      bh0[j][0] = *(const bf16x8*)(Brd + curbuf + (j << 11));
      bh0[j][1] = *(const bf16x8*)(Brd + curbuf + (j << 11) + 1024);
    }
#pragma unroll
    for (int j = 0; j < 2; ++j) {
      bh1[j][0] = *(const bf16x8*)(Brd + curbuf + 4096 + (j << 11));
      bh1[j][1] = *(const bf16x8*)(Brd + curbuf + 4096 + (j << 11) + 1024);
    }
    // ---- ph0: Q(m0,n0) — needs alo+bh0 (12 oldest); bh1 stays in flight ----
    asm volatile("s_waitcnt lgkmcnt(4)" ::: "memory");
    __builtin_amdgcn_sched_barrier(0);
    __builtin_amdgcn_s_setprio(1);
#pragma unroll
    for (int kk = 0; kk < 2; ++kk)
#pragma unroll
      for (int i = 0; i < 4; ++i)
#pragma unroll
        for (int j = 0; j < 2; ++j)
          acc[i][j] = __builtin_amdgcn_mfma_f32_16x16x32_bf16(
              alo[i][kk], bh0[j][kk], acc[i][j], 0, 0, 0);
    __builtin_amdgcn_s_setprio(0);

    // ---- issue ahi(8) under ph0; ph1: Q(m0,n1) needs bh1 ----
#pragma unroll
    for (int i = 0; i < 4; ++i) {
      ahi[i][0] = *(const bf16x8*)(Ard + curbuf + 8192 + (i << 11));
      ahi[i][1] = *(const bf16x8*)(Ard + curbuf + 8192 + (i << 11) + 1024);
    }
    asm volatile("s_waitcnt lgkmcnt(8)" ::: "memory");  // bh1 done, ahi in flight
    __builtin_amdgcn_sched_barrier(0);
    __builtin_amdgcn_s_setprio(1);
#pragma unroll
    for (int kk = 0; kk < 2; ++kk)
#pragma unroll
      for (int i = 0; i < 4; ++i)
#pragma unroll
        for (int j = 0; j < 2; ++j)
          acc[i][2 + j] = __builtin_amdgcn_mfma_f32_16x16x32_bf16(
              alo[i][kk], bh1[j][kk], acc[i][2 + j], 0, 0, 0);
    __builtin_amdgcn_s_setprio(0);
    __builtin_amdgcn_s_barrier();          // all waves' B reads of kt complete

    // ---- ph2: Q(m1,n1); stage B(kt+2) ----
    if (kt < 14) STGB(curbuf, kt + 2);
    asm volatile("s_waitcnt lgkmcnt(0)" ::: "memory");  // ahi done
    __builtin_amdgcn_sched_barrier(0);
    __builtin_amdgcn_s_setprio(1);
#pragma unroll
    for (int kk = 0; kk < 2; ++kk)
#pragma unroll
      for (int i = 0; i < 4; ++i)
#pragma unroll
        for (int j = 0; j < 2; ++j)
          acc[4 + i][2 + j] = __builtin_amdgcn_mfma_f32_16x16x32_bf16(
              ahi[i][kk], bh1[j][kk], acc[4 + i][2 + j], 0, 0, 0);
    __builtin_amdgcn_s_setprio(0);
    __builtin_amdgcn_s_barrier();          // all waves' A reads of kt complete

    // ---- ph3: Q(m1,n0) — regs held; stage A(kt+2) ----
    if (kt < 14) STGA(curbuf, kt + 2);
    __builtin_amdgcn_s_setprio(1);
#pragma unroll
    for (int kk = 0; kk < 2; ++kk)
#pragma unroll
      for (int i = 0; i < 4; ++i)
#pragma unroll
        for (int j = 0; j < 2; ++j)
          acc[4 + i][j] = __builtin_amdgcn_mfma_f32_16x16x32_bf16(
              ahi[i][kk], bh0[j][kk], acc[4 + i][j], 0, 0, 0);
    __builtin_amdgcn_s_setprio(0);
    if (kt == 14) asm volatile("s_waitcnt vmcnt(0)" ::: "memory");
    else          asm volatile("s_waitcnt vmcnt(8)" ::: "memory");
    __builtin_amdgcn_s_barrier();          // publish buffer of tile kt+1
  }

  // epilogue: out[n*4096 + m]; 4 acc regs = consecutive m -> float4 store
  const int mbase = (mp << 8) + (wm << 7) + ((lane >> 4) << 2);
  const int nbase = (np << 8) + (wn << 6) + (lane & 15);
#pragma unroll
  for (int mi = 0; mi < 8; ++mi)
#pragma unroll
    for (int ni = 0; ni < 4; ++ni)
      *(f32x4*)(out + (size_t)(nbase + ni * 16) * 4096 + mbase + mi * 16) =
          acc[mi][ni];
#undef STGA
#undef STGB
}

// ---------- launcher ----------
// setup_inputs order: 0:x 1:qweight_V 2:qzeros_V 3:scales_V 4:g_idx_V
//                     5:qweight_U 6:qzeros_U 7:scales_U 8:g_idx_U 9:S
extern "C" void kernel_launch(void* const* d_in, const int* in_sizes, int n_in,
                              void* d_out, int out_size, void* d_ws, size_t ws_size,
                              hipStream_t stream) {
  const int*   qw_V = (const int*)d_in[1];
  const int*   qz_V = (const int*)d_in[2];
  const float* sc_V = (const float*)d_in[3];
  const int*   qw_U = (const int*)d_in[5];
  const int*   qz_U = (const int*)d_in[6];
  const float* sc_U = (const float*)d_in[7];
  const float* S    = (const float*)d_in[9];

  short* A = (short*)d_ws;                  // 8 MB fragment-major P
  short* B = (short*)d_ws + 4096 * 1024;    // 8 MB fragment-major Qt
  float* out = (float*)d_out;

  dequant_fused<<<4096, 256, 0, stream>>>(qw_V, qz_V, sc_V, S, A,
                                          qw_U, qz_U, sc_U, B);
  gemm256<<<256, 512, 0, stream>>>(A, B, out);
}